// Round 11
// baseline (126.152 us; speedup 1.0000x reference)
//
#include <hip/hip_runtime.h>
#include <hip/hip_bf16.h>

// MHGAT: B=8, J=2048, C=256, K=32, H=8, D=32; M = B*J = 16384
// World: all float tensors fp32; nbr int32; out fp32.
// Round 11: attn v7 — 2 queries per block (grid 8192): halves prologue/koff
// cost, 8 barriers per query-pair (was 10), q1's vp loads issued before q0's
// tail and held in registers. LDS 14 KB, VGPR ~56 -> still 8 blocks/CU
// (r7 lesson: never trade occupancy). prep/qkv_mfma unchanged.

typedef short bf16x8 __attribute__((ext_vector_type(8)));
typedef float f32x4  __attribute__((ext_vector_type(4)));
typedef float f32x2  __attribute__((ext_vector_type(2)));

__device__ __forceinline__ float bf2f(unsigned short u) {
    union { unsigned int i; float f; } c; c.i = ((unsigned int)u) << 16; return c.f;
}
__device__ __forceinline__ unsigned short f2bf(float f) {
    union { float f; unsigned int i; } c; c.f = f;
    unsigned int r = c.i + 0x7FFFu + ((c.i >> 16) & 1u);  // RNE
    return (unsigned short)(r >> 16);
}
// 2 bf16 packed in a dword -> 2 fp32 with exactly 2 bit-ops.
__device__ __forceinline__ f32x2 upk(unsigned int u) {
    union { unsigned int i; float f; } lo, hi;
    lo.i = u << 16;
    hi.i = u & 0xffff0000u;
    return (f32x2){lo.f, hi.f};
}

__device__ __forceinline__ void gld_lds16(void* lds, const void* g) {
    __builtin_amdgcn_global_load_lds(
        (const __attribute__((address_space(1))) unsigned int*)g,
        (__attribute__((address_space(3))) unsigned int*)lds,
        16, 0, 0);
}

// ---------------------------------------------------------------------------
// Prep (unchanged): x fp32->bf16; Wq/Wk transposed bf16; Weff = Wv@Wp folded.
// ---------------------------------------------------------------------------
__global__ __launch_bounds__(256) void prep(
    const float* __restrict__ x,
    const float* __restrict__ Wq, const float* __restrict__ Wk,
    const float* __restrict__ Wv, const float* __restrict__ Wp,
    unsigned short* __restrict__ xb, unsigned short* __restrict__ Wt)
{
    const int blk = blockIdx.x, tid = threadIdx.x;
    if (blk < 4096) {
        int t = blk * 256 + tid;
        float4 f = ((const float4*)x)[t];
        ushort4 u;
        u.x = f2bf(f.x); u.y = f2bf(f.y); u.z = f2bf(f.z); u.w = f2bf(f.w);
        ((ushort4*)xb)[t] = u;
        return;
    }
    int wi = blk - 4096;
    int w = wi >> 8, n = wi & 255, t = tid;       // t = k index
    if (w == 0) {
        Wt[(size_t)n * 256 + t] = f2bf(Wq[(size_t)t * 256 + n]);
    } else if (w == 1) {
        Wt[(size_t)(256 + n) * 256 + t] = f2bf(Wk[(size_t)t * 256 + n]);
    } else {
        int h = n >> 5, c = n & 31;
        float acc = 0.f;
#pragma unroll
        for (int d = 0; d < 32; d++)
            acc += Wv[(size_t)t * 256 + h * 32 + d] * Wp[(size_t)(h * 32 + d) * 32 + c];
        Wt[(size_t)(512 + n) * 256 + t] = f2bf(acc);
    }
}

// ---------------------------------------------------------------------------
// QKV GEMM (unchanged): xb bf16 @ Wt[z][n][k] -> bf16. z: 0->q,1->k,2->VP.
// ---------------------------------------------------------------------------
__global__ __launch_bounds__(256) void qkv_mfma(
    const unsigned short* __restrict__ xb,
    const unsigned short* __restrict__ Wt,
    unsigned short* __restrict__ Q, unsigned short* __restrict__ Kp,
    unsigned short* __restrict__ VP)
{
    __shared__ unsigned short Als[128][64];
    __shared__ unsigned short Bls[128][64];

    const unsigned short* Wb = Wt + (size_t)blockIdx.z * 65536;
    unsigned short* Y = (blockIdx.z == 0) ? Q : (blockIdx.z == 1) ? Kp : VP;

    const int row0 = blockIdx.x * 128;
    const int col0 = blockIdx.y * 128;
    const int tid  = threadIdx.x;
    const int w    = tid >> 6, l = tid & 63;
    const int wm   = (w >> 1) * 64, wn = (w & 1) * 64;
    const int lm   = l & 15, quad = l >> 4;

    f32x4 acc[4][4];
#pragma unroll
    for (int i = 0; i < 4; i++)
#pragma unroll
        for (int j = 0; j < 4; j++) acc[i][j] = (f32x4){0.f, 0.f, 0.f, 0.f};

    const char* Ab = (const char*)(xb + (size_t)row0 * 256);
    const char* Bb = (const char*)(Wb + (size_t)col0 * 256);

    for (int k0 = 0; k0 < 256; k0 += 64) {
#pragma unroll
        for (int i = 0; i < 4; i++) {
            int s = i * 256 + tid;
            int r = s >> 3, c = s & 7;
            size_t go = (size_t)r * 512 + (size_t)k0 * 2 + c * 16;
            gld_lds16((char*)Als + s * 16, Ab + go);
            gld_lds16((char*)Bls + s * 16, Bb + go);
        }
        __syncthreads();

#pragma unroll
        for (int kk = 0; kk < 64; kk += 32) {
            bf16x8 a[4], b[4];
#pragma unroll
            for (int tm = 0; tm < 4; tm++)
                a[tm] = *(const bf16x8*)&Als[wm + tm * 16 + lm][kk + quad * 8];
#pragma unroll
            for (int tn = 0; tn < 4; tn++)
                b[tn] = *(const bf16x8*)&Bls[wn + tn * 16 + lm][kk + quad * 8];
#pragma unroll
            for (int tm = 0; tm < 4; tm++)
#pragma unroll
                for (int tn = 0; tn < 4; tn++)
                    acc[tm][tn] = __builtin_amdgcn_mfma_f32_16x16x32_bf16(
                        a[tm], b[tn], acc[tm][tn], 0, 0, 0);
        }
        __syncthreads();
    }

#pragma unroll
    for (int tm = 0; tm < 4; tm++) {
        int rbase = row0 + wm + tm * 16 + quad * 4;
#pragma unroll
        for (int tn = 0; tn < 4; tn++) {
            int col = col0 + wn + tn * 16 + lm;
#pragma unroll
            for (int r = 0; r < 4; r++)
                Y[(size_t)(rbase + r) * 256 + col] = f2bf(acc[tm][tn][r]);
        }
    }
}

// ---------------------------------------------------------------------------
// Attention v7: 2 queries per block, grid 8192. XCD swizzle b = blk&7.
// Per query: coalesced 512-B row reads (r8), dword unpack (r9).
// q1 phase-B loads issued before q0's tail, held in registers.
// ---------------------------------------------------------------------------
__global__ __launch_bounds__(256) void attn_all(
    const unsigned short* __restrict__ qb,   // [16384,256] bf16
    const unsigned short* __restrict__ kb,   // [16384,256] bf16
    const unsigned short* __restrict__ vp,   // [16384,256] bf16 (VP = v@Wp)
    const int*            __restrict__ nbr,  // [16384,32]
    float*                __restrict__ out)  // [16384,32] fp32
{
    __shared__ int   koff[64];       // [ql][kk] nbr*256 element offsets
    __shared__ float sc[2][8 * 33];  // [ql][h][kk]
    __shared__ float pw[2][8 * 33];
    __shared__ float redB[8 * 264];  // [g][e], e-stride 264 (reused q0/q1)
    __shared__ float red2[256];      // [e] after g-sum (reused)

    const int b   = blockIdx.x & 7;
    const int jt  = blockIdx.x >> 3;         // 0..1023
    const int bj0 = (b << 11) + jt * 2;      // first of 2 queries
    const int tid = threadIdx.x;

    if (tid < 64) koff[tid] = nbr[(size_t)bj0 * 32 + tid] << 8;

    const int w    = tid >> 6;       // wave 0..3
    const int l    = tid & 63;
    const int lh   = l & 31;         // lane within half-wave
    const int half = l >> 5;
    const int hA   = lh >> 2;        // head owning elems lh*8..lh*8+7
    const int g    = 2 * w + half;   // phase-B group 0..7
    const size_t bbase = (size_t)b << 19;   // b*2048*256

    // both queries' q fragments (no koff dependency)
    uint4 qu0 = *(const uint4*)(qb + (size_t)(bj0 + 0) * 256 + lh * 8);
    uint4 qu1 = *(const uint4*)(qb + (size_t)(bj0 + 1) * 256 + lh * 8);
    __syncthreads();   // B1: koff ready

    // ---- Phase A: scores for both queries ----
#pragma unroll
    for (int ql = 0; ql < 2; ql++) {
        uint4 qu = ql ? qu1 : qu0;
        f32x2 qf[4];
        qf[0] = upk(qu.x); qf[1] = upk(qu.y); qf[2] = upk(qu.z); qf[3] = upk(qu.w);
#pragma unroll
        for (int p = 0; p < 4; p++) {
            const int kkA = w * 8 + 2 * p + half;
            uint4 u = *(const uint4*)(kb + bbase + koff[ql * 32 + kkA] + lh * 8);
            f32x2 a2 = (f32x2){0.f, 0.f};
            a2 += upk(u.x) * qf[0];
            a2 += upk(u.y) * qf[1];
            a2 += upk(u.z) * qf[2];
            a2 += upk(u.w) * qf[3];
            float acc = a2.x + a2.y;
            acc += __shfl_xor(acc, 1);
            acc += __shfl_xor(acc, 2);
            if ((l & 3) == 0) {
                float s = acc * 0.17677669529663687f;   // 1/sqrt(32)
                s = (s > 0.f) ? s : 0.2f * s;           // leaky_relu 0.2
                sc[ql][hA * 33 + kkA] = s;
            }
        }
    }
    __syncthreads();   // B2

    // ---- softmax per head, both queries: lane=(kk2,h2) ----
    {
        const int h2  = 2 * w + half;
        const int kk2 = lh;
#pragma unroll
        for (int ql = 0; ql < 2; ql++) {
            float s = sc[ql][h2 * 33 + kk2];
            float mx = s;
#pragma unroll
            for (int m = 16; m >= 1; m >>= 1) mx = fmaxf(mx, __shfl_xor(mx, m));
            float e = __expf(s - mx);
            float sum = e;
#pragma unroll
            for (int m = 16; m >= 1; m >>= 1) sum += __shfl_xor(sum, m);
            pw[ql][h2 * 33 + kk2] = e / sum;
        }
    }
    __syncthreads();   // B3

    // ---- Phase B q0 (and pre-issue q1's vp loads, held in regs) ----
    uint4 vu1[4];
    {
        f32x2 a0 = (f32x2){0.f,0.f}, a1 = a0, a2v = a0, a3 = a0;
        uint4 vu0[4];
#pragma unroll
        for (int p = 0; p < 4; p++) {
            const int kkB = p * 8 + g;
            vu0[p] = *(const uint4*)(vp + bbase + koff[kkB] + lh * 8);
        }
#pragma unroll
        for (int p = 0; p < 4; p++) {
            const int kkB = p * 8 + g;
            vu1[p] = *(const uint4*)(vp + bbase + koff[32 + kkB] + lh * 8);
        }
#pragma unroll
        for (int p = 0; p < 4; p++) {
            const int kkB = p * 8 + g;
            const float wgt = pw[0][hA * 33 + kkB];
            const f32x2 w2 = (f32x2){wgt, wgt};
            a0  += upk(vu0[p].x) * w2;
            a1  += upk(vu0[p].y) * w2;
            a2v += upk(vu0[p].z) * w2;
            a3  += upk(vu0[p].w) * w2;
        }
        float* rb = &redB[g * 264 + lh * 8];
        *(float4*)(rb)     = make_float4(a0.x, a0.y, a1.x, a1.y);
        *(float4*)(rb + 4) = make_float4(a2v.x, a2v.y, a3.x, a3.y);
    }
    __syncthreads();   // B4

    // g-sum q0
    {
        float s = 0.f;
#pragma unroll
        for (int gg = 0; gg < 8; gg++) s += redB[gg * 264 + tid];
        red2[tid] = s;
    }
    __syncthreads();   // B5 (redB reads done; red2 ready)

    // h-sum+store q0 (32 threads) overlapped with phase B q1 (all threads)
    if (tid < 32) {
        float o = 0.f;
#pragma unroll
        for (int h = 0; h < 8; h++) o += red2[h * 32 + tid];
        out[(size_t)(bj0 + 0) * 32 + tid] = o;
    }
    {
        f32x2 a0 = (f32x2){0.f,0.f}, a1 = a0, a2v = a0, a3 = a0;
#pragma unroll
        for (int p = 0; p < 4; p++) {
            const int kkB = p * 8 + g;
            const float wgt = pw[1][hA * 33 + kkB];
            const f32x2 w2 = (f32x2){wgt, wgt};
            a0  += upk(vu1[p].x) * w2;
            a1  += upk(vu1[p].y) * w2;
            a2v += upk(vu1[p].z) * w2;
            a3  += upk(vu1[p].w) * w2;
        }
        float* rb = &redB[g * 264 + lh * 8];
        *(float4*)(rb)     = make_float4(a0.x, a0.y, a1.x, a1.y);
        *(float4*)(rb + 4) = make_float4(a2v.x, a2v.y, a3.x, a3.y);
    }
    __syncthreads();   // B6

    // g-sum q1
    {
        float s = 0.f;
#pragma unroll
        for (int gg = 0; gg < 8; gg++) s += redB[gg * 264 + tid];
        red2[tid] = s;
    }
    __syncthreads();   // B7

    if (tid < 32) {
        float o = 0.f;
#pragma unroll
        for (int h = 0; h < 8; h++) o += red2[h * 32 + tid];
        out[(size_t)(bj0 + 1) * 32 + tid] = o;
    }
}

// ---------------------------------------------------------------------------
// Tier 0 fallback (tiny ws): fully fused fp32, zero workspace. Slow, correct.
// ---------------------------------------------------------------------------
__global__ __launch_bounds__(256) void fused_all(
    const float* __restrict__ X, const int* __restrict__ nbr,
    const float* __restrict__ Wq, const float* __restrict__ Wk,
    const float* __restrict__ Wv, const float* __restrict__ Wp,
    float* __restrict__ out)
{
    __shared__ float xr[256], qrow[256], xn[256];
    __shared__ float vn[32][256];
    __shared__ int   nb[32];
    __shared__ float sc[32][8], pwv[32][8];
    __shared__ float sp[256], hd[256];
    __shared__ float red[8][32];

    const int bj = blockIdx.x, b = bj >> 11, tid = threadIdx.x;

    xr[tid] = X[(size_t)bj * 256 + tid];
    if (tid < 32) nb[tid] = nbr[(size_t)bj * 32 + tid];
    __syncthreads();

    {
        float acc = 0.f;
#pragma unroll 8
        for (int c = 0; c < 256; c++) acc += xr[c] * Wq[(size_t)c * 256 + tid];
        qrow[tid] = acc;
    }
    __syncthreads();

    for (int i = 0; i < 32; i++) {
        size_t r = (size_t)(b * 2048 + nb[i]);
        xn[tid] = X[r * 256 + tid];
        __syncthreads();
        float ka = 0.f, va = 0.f;
#pragma unroll 8
        for (int c = 0; c < 256; c++) {
            float xc = xn[c];
            ka += xc * Wk[(size_t)c * 256 + tid];
            va += xc * Wv[(size_t)c * 256 + tid];
        }
        vn[i][tid] = va;
        sp[tid] = qrow[tid] * ka;
        __syncthreads();
        if (tid < 8) {
            float s = 0.f;
#pragma unroll
            for (int d = 0; d < 32; d++) s += sp[tid * 32 + d];
            s *= 0.17677669529663687f;
            s = (s > 0.f) ? s : 0.2f * s;
            sc[i][tid] = s;
        }
        __syncthreads();
    }

    {
        const int h = tid & 7, kk = tid >> 3;
        float mx = -1e30f;
#pragma unroll
        for (int i = 0; i < 32; i++) mx = fmaxf(mx, sc[i][h]);
        float ssum = 0.f;
#pragma unroll
        for (int i = 0; i < 32; i++) ssum += __expf(sc[i][h] - mx);
        pwv[kk][h] = __expf(sc[kk][h] - mx) / ssum;
    }
    __syncthreads();

    {
        const int h2 = tid >> 5;
        float acc = 0.f;
#pragma unroll 8
        for (int i = 0; i < 32; i++) acc += pwv[i][h2] * vn[i][tid];
        hd[tid] = acc;
    }
    __syncthreads();

    {
        const int c = tid & 31, ch = tid >> 5;
        float p = 0.f;
#pragma unroll
        for (int i = 0; i < 32; i++) { int r = ch * 32 + i; p += hd[r] * Wp[r * 32 + c]; }
        red[ch][c] = p;
    }
    __syncthreads();

    if (tid < 32) {
        float o = 0.f;
#pragma unroll
        for (int i = 0; i < 8; i++) o += red[i][tid];
        out[(size_t)bj * 32 + tid] = o;
    }
}

extern "C" void kernel_launch(void* const* d_in, const int* in_sizes, int n_in,
                              void* d_out, int out_size, void* d_ws, size_t ws_size,
                              hipStream_t stream) {
    const float* x   = (const float*)d_in[0];
    const int*   nbr = (const int*)d_in[1];
    const float* Wq  = (const float*)d_in[2];
    const float* Wk  = (const float*)d_in[3];
    const float* Wv  = (const float*)d_in[4];
    const float* Wp  = (const float*)d_in[5];
    float*       out = (float*)d_out;

    const size_t ME   = (size_t)16384 * 256;
    const size_t need = (4 * ME + 3 * 65536) * sizeof(unsigned short);  // ~34 MB

    if (ws_size >= need) {
        unsigned short* q  = (unsigned short*)d_ws;
        unsigned short* k  = q + ME;
        unsigned short* vp = k + ME;
        unsigned short* xb = vp + ME;
        unsigned short* Wt = xb + ME;

        prep<<<4096 + 768, 256, 0, stream>>>(x, Wq, Wk, Wv, Wp, xb, Wt);
        qkv_mfma<<<dim3(128, 2, 3), 256, 0, stream>>>(xb, Wt, q, k, vp);
        attn_all<<<8192, 256, 0, stream>>>(q, k, vp, nbr, out);
    } else {
        fused_all<<<16384, 256, 0, stream>>>(x, nbr, Wq, Wk, Wv, Wp, out);
    }
}

// Round 12
// 124.369 us; speedup vs baseline: 1.0143x; 1.0143x over previous
//
#include <hip/hip_runtime.h>
#include <hip/hip_bf16.h>

// MHGAT: B=8, J=2048, C=256, K=32, H=8, D=32; M = B*J = 16384
// World: all float tensors fp32; nbr int32; out fp32.
// Round 12: r10 base (best: 124.9) + per-lane koff loads (half-wave-uniform
// addresses -> TA broadcast), removing the koff LDS stage and barrier B1.
// prep/qkv_mfma unchanged.

typedef short bf16x8 __attribute__((ext_vector_type(8)));
typedef float f32x4  __attribute__((ext_vector_type(4)));
typedef float f32x2  __attribute__((ext_vector_type(2)));

__device__ __forceinline__ float bf2f(unsigned short u) {
    union { unsigned int i; float f; } c; c.i = ((unsigned int)u) << 16; return c.f;
}
__device__ __forceinline__ unsigned short f2bf(float f) {
    union { float f; unsigned int i; } c; c.f = f;
    unsigned int r = c.i + 0x7FFFu + ((c.i >> 16) & 1u);  // RNE
    return (unsigned short)(r >> 16);
}
// 2 bf16 packed in a dword -> 2 fp32 with exactly 2 bit-ops.
__device__ __forceinline__ f32x2 upk(unsigned int u) {
    union { unsigned int i; float f; } lo, hi;
    lo.i = u << 16;
    hi.i = u & 0xffff0000u;
    return (f32x2){lo.f, hi.f};
}

__device__ __forceinline__ void gld_lds16(void* lds, const void* g) {
    __builtin_amdgcn_global_load_lds(
        (const __attribute__((address_space(1))) unsigned int*)g,
        (__attribute__((address_space(3))) unsigned int*)lds,
        16, 0, 0);
}

// ---------------------------------------------------------------------------
// Prep (unchanged): x fp32->bf16; Wq/Wk transposed bf16; Weff = Wv@Wp folded.
// ---------------------------------------------------------------------------
__global__ __launch_bounds__(256) void prep(
    const float* __restrict__ x,
    const float* __restrict__ Wq, const float* __restrict__ Wk,
    const float* __restrict__ Wv, const float* __restrict__ Wp,
    unsigned short* __restrict__ xb, unsigned short* __restrict__ Wt)
{
    const int blk = blockIdx.x, tid = threadIdx.x;
    if (blk < 4096) {
        int t = blk * 256 + tid;
        float4 f = ((const float4*)x)[t];
        ushort4 u;
        u.x = f2bf(f.x); u.y = f2bf(f.y); u.z = f2bf(f.z); u.w = f2bf(f.w);
        ((ushort4*)xb)[t] = u;
        return;
    }
    int wi = blk - 4096;
    int w = wi >> 8, n = wi & 255, t = tid;       // t = k index
    if (w == 0) {
        Wt[(size_t)n * 256 + t] = f2bf(Wq[(size_t)t * 256 + n]);
    } else if (w == 1) {
        Wt[(size_t)(256 + n) * 256 + t] = f2bf(Wk[(size_t)t * 256 + n]);
    } else {
        int h = n >> 5, c = n & 31;
        float acc = 0.f;
#pragma unroll
        for (int d = 0; d < 32; d++)
            acc += Wv[(size_t)t * 256 + h * 32 + d] * Wp[(size_t)(h * 32 + d) * 32 + c];
        Wt[(size_t)(512 + n) * 256 + t] = f2bf(acc);
    }
}

// ---------------------------------------------------------------------------
// QKV GEMM (unchanged): xb bf16 @ Wt[z][n][k] -> bf16. z: 0->q,1->k,2->VP.
// ---------------------------------------------------------------------------
__global__ __launch_bounds__(256) void qkv_mfma(
    const unsigned short* __restrict__ xb,
    const unsigned short* __restrict__ Wt,
    unsigned short* __restrict__ Q, unsigned short* __restrict__ Kp,
    unsigned short* __restrict__ VP)
{
    __shared__ unsigned short Als[128][64];
    __shared__ unsigned short Bls[128][64];

    const unsigned short* Wb = Wt + (size_t)blockIdx.z * 65536;
    unsigned short* Y = (blockIdx.z == 0) ? Q : (blockIdx.z == 1) ? Kp : VP;

    const int row0 = blockIdx.x * 128;
    const int col0 = blockIdx.y * 128;
    const int tid  = threadIdx.x;
    const int w    = tid >> 6, l = tid & 63;
    const int wm   = (w >> 1) * 64, wn = (w & 1) * 64;
    const int lm   = l & 15, quad = l >> 4;

    f32x4 acc[4][4];
#pragma unroll
    for (int i = 0; i < 4; i++)
#pragma unroll
        for (int j = 0; j < 4; j++) acc[i][j] = (f32x4){0.f, 0.f, 0.f, 0.f};

    const char* Ab = (const char*)(xb + (size_t)row0 * 256);
    const char* Bb = (const char*)(Wb + (size_t)col0 * 256);

    for (int k0 = 0; k0 < 256; k0 += 64) {
#pragma unroll
        for (int i = 0; i < 4; i++) {
            int s = i * 256 + tid;
            int r = s >> 3, c = s & 7;
            size_t go = (size_t)r * 512 + (size_t)k0 * 2 + c * 16;
            gld_lds16((char*)Als + s * 16, Ab + go);
            gld_lds16((char*)Bls + s * 16, Bb + go);
        }
        __syncthreads();

#pragma unroll
        for (int kk = 0; kk < 64; kk += 32) {
            bf16x8 a[4], b[4];
#pragma unroll
            for (int tm = 0; tm < 4; tm++)
                a[tm] = *(const bf16x8*)&Als[wm + tm * 16 + lm][kk + quad * 8];
#pragma unroll
            for (int tn = 0; tn < 4; tn++)
                b[tn] = *(const bf16x8*)&Bls[wn + tn * 16 + lm][kk + quad * 8];
#pragma unroll
            for (int tm = 0; tm < 4; tm++)
#pragma unroll
                for (int tn = 0; tn < 4; tn++)
                    acc[tm][tn] = __builtin_amdgcn_mfma_f32_16x16x32_bf16(
                        a[tm], b[tn], acc[tm][tn], 0, 0, 0);
        }
        __syncthreads();
    }

#pragma unroll
    for (int tm = 0; tm < 4; tm++) {
        int rbase = row0 + wm + tm * 16 + quad * 4;
#pragma unroll
        for (int tn = 0; tn < 4; tn++) {
            int col = col0 + wn + tn * 16 + lm;
#pragma unroll
            for (int r = 0; r < 4; r++)
                Y[(size_t)(rbase + r) * 256 + col] = f2bf(acc[tm][tn][r]);
        }
    }
}

// ---------------------------------------------------------------------------
// Attention v8 (r10 structure): one block per (b,j), 16384 blocks.
// XCD swizzle b = blk&7. Per-lane koff loads (half-wave-uniform address ->
// broadcast), no koff LDS, no B1 barrier. All 8 row loads issued up front;
// vp values ride registers across the softmax barriers. 4 barriers total.
// ---------------------------------------------------------------------------
__global__ __launch_bounds__(256) void attn_all(
    const unsigned short* __restrict__ qb,   // [16384,256] bf16
    const unsigned short* __restrict__ kb,   // [16384,256] bf16
    const unsigned short* __restrict__ vp,   // [16384,256] bf16 (VP = v@Wp)
    const int*            __restrict__ nbr,  // [16384,32]
    float*                __restrict__ out)  // [16384,32] fp32
{
    __shared__ float sc[8 * 33];    // [h][kk]
    __shared__ float pw[8 * 33];    // [h][kk]
    __shared__ float redB[8 * 264]; // [g][e], e-stride 264
    __shared__ float red2[256];     // [e] after g-sum

    const int b   = blockIdx.x & 7;
    const int j   = blockIdx.x >> 3;
    const int bj  = (b << 11) + j;
    const int tid = threadIdx.x;

    const int w    = tid >> 6;       // wave 0..3
    const int l    = tid & 63;
    const int lh   = l & 31;         // lane within half-wave
    const int half = l >> 5;
    const int hA   = lh >> 2;        // head owning elems lh*8..lh*8+7
    const int g    = 2 * w + half;   // phase-B group 0..7
    const size_t bbase = (size_t)b << 19;   // b*2048*256
    const int* nrow = nbr + (size_t)bj * 32;

    // q fragment load (independent of everything).
    uint4 qu = *(const uint4*)(qb + (size_t)bj * 256 + lh * 8);

    // per-lane neighbor indices (half-wave-uniform addresses -> broadcast)
    int koA[4], koB[4];
#pragma unroll
    for (int p = 0; p < 4; p++) koA[p] = nrow[w * 8 + 2 * p + half] << 8;
#pragma unroll
    for (int p = 0; p < 4; p++) koB[p] = nrow[p * 8 + g] << 8;

    // ---- issue ALL 8 row loads up front ----
    uint4 ku[4], vu[4];
#pragma unroll
    for (int p = 0; p < 4; p++)
        ku[p] = *(const uint4*)(kb + bbase + koA[p] + lh * 8);
#pragma unroll
    for (int p = 0; p < 4; p++)
        vu[p] = *(const uint4*)(vp + bbase + koB[p] + lh * 8);

    f32x2 qf[4];
    qf[0] = upk(qu.x); qf[1] = upk(qu.y); qf[2] = upk(qu.z); qf[3] = upk(qu.w);

    // ---- Phase A: scores from ku ----
#pragma unroll
    for (int p = 0; p < 4; p++) {
        const int kkA = w * 8 + 2 * p + half;
        f32x2 a2 = (f32x2){0.f, 0.f};
        a2 += upk(ku[p].x) * qf[0];
        a2 += upk(ku[p].y) * qf[1];
        a2 += upk(ku[p].z) * qf[2];
        a2 += upk(ku[p].w) * qf[3];
        float acc = a2.x + a2.y;
        acc += __shfl_xor(acc, 1);
        acc += __shfl_xor(acc, 2);
        if ((l & 3) == 0) {
            float s = acc * 0.17677669529663687f;   // 1/sqrt(32)
            s = (s > 0.f) ? s : 0.2f * s;           // leaky_relu 0.2
            sc[hA * 33 + kkA] = s;
        }
    }
    __syncthreads();   // B1: sc ready

    // ---- softmax over kk per head: lane=(kk2,h2) ----
    {
        const int h2  = 2 * w + half;
        const int kk2 = lh;
        float s = sc[h2 * 33 + kk2];
        float mx = s;
#pragma unroll
        for (int m = 16; m >= 1; m >>= 1) mx = fmaxf(mx, __shfl_xor(mx, m));
        float e = __expf(s - mx);
        float sum = e;
#pragma unroll
        for (int m = 16; m >= 1; m >>= 1) sum += __shfl_xor(sum, m);
        pw[h2 * 33 + kk2] = e / sum;
    }
    __syncthreads();   // B2: pw ready

    // ---- Phase B: weighted accumulate from prefetched vu ----
    {
        f32x2 a0 = (f32x2){0.f,0.f}, a1 = a0, a2v = a0, a3 = a0;
#pragma unroll
        for (int p = 0; p < 4; p++) {
            const int kkB = p * 8 + g;
            const float wgt = pw[hA * 33 + kkB];
            const f32x2 w2 = (f32x2){wgt, wgt};
            a0  += upk(vu[p].x) * w2;
            a1  += upk(vu[p].y) * w2;
            a2v += upk(vu[p].z) * w2;
            a3  += upk(vu[p].w) * w2;
        }
        float* rb = &redB[g * 264 + lh * 8];
        *(float4*)(rb)     = make_float4(a0.x, a0.y, a1.x, a1.y);
        *(float4*)(rb + 4) = make_float4(a2v.x, a2v.y, a3.x, a3.y);
    }
    __syncthreads();   // B3: redB ready

    // ---- tail: g-sum with all 256 threads, then h-sum with 32 ----
    {
        float s = 0.f;
#pragma unroll
        for (int gg = 0; gg < 8; gg++) s += redB[gg * 264 + tid];
        red2[tid] = s;
    }
    __syncthreads();   // B4: red2 ready

    if (tid < 32) {
        float o = 0.f;
#pragma unroll
        for (int h = 0; h < 8; h++) o += red2[h * 32 + tid];
        out[(size_t)bj * 32 + tid] = o;
    }
}

// ---------------------------------------------------------------------------
// Tier 0 fallback (tiny ws): fully fused fp32, zero workspace. Slow, correct.
// ---------------------------------------------------------------------------
__global__ __launch_bounds__(256) void fused_all(
    const float* __restrict__ X, const int* __restrict__ nbr,
    const float* __restrict__ Wq, const float* __restrict__ Wk,
    const float* __restrict__ Wv, const float* __restrict__ Wp,
    float* __restrict__ out)
{
    __shared__ float xr[256], qrow[256], xn[256];
    __shared__ float vn[32][256];
    __shared__ int   nb[32];
    __shared__ float sc[32][8], pwv[32][8];
    __shared__ float sp[256], hd[256];
    __shared__ float red[8][32];

    const int bj = blockIdx.x, b = bj >> 11, tid = threadIdx.x;

    xr[tid] = X[(size_t)bj * 256 + tid];
    if (tid < 32) nb[tid] = nbr[(size_t)bj * 32 + tid];
    __syncthreads();

    {
        float acc = 0.f;
#pragma unroll 8
        for (int c = 0; c < 256; c++) acc += xr[c] * Wq[(size_t)c * 256 + tid];
        qrow[tid] = acc;
    }
    __syncthreads();

    for (int i = 0; i < 32; i++) {
        size_t r = (size_t)(b * 2048 + nb[i]);
        xn[tid] = X[r * 256 + tid];
        __syncthreads();
        float ka = 0.f, va = 0.f;
#pragma unroll 8
        for (int c = 0; c < 256; c++) {
            float xc = xn[c];
            ka += xc * Wk[(size_t)c * 256 + tid];
            va += xc * Wv[(size_t)c * 256 + tid];
        }
        vn[i][tid] = va;
        sp[tid] = qrow[tid] * ka;
        __syncthreads();
        if (tid < 8) {
            float s = 0.f;
#pragma unroll
            for (int d = 0; d < 32; d++) s += sp[tid * 32 + d];
            s *= 0.17677669529663687f;
            s = (s > 0.f) ? s : 0.2f * s;
            sc[i][tid] = s;
        }
        __syncthreads();
    }

    {
        const int h = tid & 7, kk = tid >> 3;
        float mx = -1e30f;
#pragma unroll
        for (int i = 0; i < 32; i++) mx = fmaxf(mx, sc[i][h]);
        float ssum = 0.f;
#pragma unroll
        for (int i = 0; i < 32; i++) ssum += __expf(sc[i][h] - mx);
        pwv[kk][h] = __expf(sc[kk][h] - mx) / ssum;
    }
    __syncthreads();

    {
        const int h2 = tid >> 5;
        float acc = 0.f;
#pragma unroll 8
        for (int i = 0; i < 32; i++) acc += pwv[i][h2] * vn[i][tid];
        hd[tid] = acc;
    }
    __syncthreads();

    {
        const int c = tid & 31, ch = tid >> 5;
        float p = 0.f;
#pragma unroll
        for (int i = 0; i < 32; i++) { int r = ch * 32 + i; p += hd[r] * Wp[r * 32 + c]; }
        red[ch][c] = p;
    }
    __syncthreads();

    if (tid < 32) {
        float o = 0.f;
#pragma unroll
        for (int i = 0; i < 8; i++) o += red[i][tid];
        out[(size_t)bj * 32 + tid] = o;
    }
}

extern "C" void kernel_launch(void* const* d_in, const int* in_sizes, int n_in,
                              void* d_out, int out_size, void* d_ws, size_t ws_size,
                              hipStream_t stream) {
    const float* x   = (const float*)d_in[0];
    const int*   nbr = (const int*)d_in[1];
    const float* Wq  = (const float*)d_in[2];
    const float* Wk  = (const float*)d_in[3];
    const float* Wv  = (const float*)d_in[4];
    const float* Wp  = (const float*)d_in[5];
    float*       out = (float*)d_out;

    const size_t ME   = (size_t)16384 * 256;
    const size_t need = (4 * ME + 3 * 65536) * sizeof(unsigned short);  // ~34 MB

    if (ws_size >= need) {
        unsigned short* q  = (unsigned short*)d_ws;
        unsigned short* k  = q + ME;
        unsigned short* vp = k + ME;
        unsigned short* xb = vp + ME;
        unsigned short* Wt = xb + ME;

        prep<<<4096 + 768, 256, 0, stream>>>(x, Wq, Wk, Wv, Wp, xb, Wt);
        qkv_mfma<<<dim3(128, 2, 3), 256, 0, stream>>>(xb, Wt, q, k, vp);
        attn_all<<<16384, 256, 0, stream>>>(q, k, vp, nbr, out);
    } else {
        fused_all<<<16384, 256, 0, stream>>>(x, nbr, Wq, Wk, Wv, Wp, out);
    }
}